// Round 11
// baseline (41.218 us; speedup 1.0000x reference)
//
#include <hip/hip_runtime.h>

#define NVELL 1024

typedef float v2 __attribute__((ext_vector_type(2)));

__device__ __forceinline__ float rcp1(float x){ return __builtin_amdgcn_rcpf(x); }
__device__ __forceinline__ v2 bc(float x){ v2 r = {x, x}; return r; }
__device__ __forceinline__ v2 rcp2(v2 x){ v2 r = {rcp1(x.x), rcp1(x.y)}; return r; }

// Lane L owns ring blocks B=2L (.x) and B=2L+1 (.y).
// blkPrev: value of quantity at block B-1; blkNext: at block B+1. Zero outside ring.
__device__ __forceinline__ v2 blkPrev(v2 p, int lane){
  float s = __shfl(p.y, (lane - 1) & 63, 64);
  v2 r; r.x = (lane >= 1) ? s : 0.f; r.y = p.x; return r;
}
__device__ __forceinline__ v2 blkNext(v2 p, int lane){
  float s = __shfl(p.x, (lane + 1) & 63, 64);
  v2 r; r.x = p.y; r.y = (lane <= 62) ? s : 0.f; return r;
}
// scalar seams on the 64-lane evens ring
__device__ __forceinline__ float sseamL(float x, int lane, int st){
  float s = __shfl(x, (lane - st) & 63, 64);
  return (lane >= st) ? s : 0.f;
}
__device__ __forceinline__ float sseamR(float x, int lane, int st){
  float s = __shfl(x, (lane + st) & 63, 64);
  return (lane + st <= 63) ? s : 0.f;
}

// ---- DPP wave-sum: row_shr 1,2,4,8 + row_bcast15 + row_bcast31, total in lane 63 ----
template<int CTRL>
__device__ __forceinline__ float dpp_add(float x) {
  float t = __int_as_float(__builtin_amdgcn_update_dpp(
      0, __float_as_int(x), CTRL, 0xf, 0xf, true));
  return x + t;
}
__device__ __forceinline__ float wavesum(float x) {
  x = dpp_add<0x111>(x);   // row_shr:1
  x = dpp_add<0x112>(x);   // row_shr:2
  x = dpp_add<0x114>(x);   // row_shr:4
  x = dpp_add<0x118>(x);   // row_shr:8
  x = dpp_add<0x142>(x);   // row_bcast15
  x = dpp_add<0x143>(x);   // row_bcast31
  return __int_as_float(__builtin_amdgcn_readlane(__float_as_int(x), 63));
}

__global__ __launch_bounds__(256, 4) void fp_step_kernel(
    const float* __restrict__ f, const float* __restrict__ v,
    const float* __restrict__ ve, const float* __restrict__ p_dv,
    const float* __restrict__ p_nu, const float* __restrict__ p_dt,
    float* __restrict__ out, int nrows)
{
  const int lane = threadIdx.x & 63;
  const int wid  = threadIdx.x >> 6;
  const int row  = blockIdx.x * 4 + wid;
  if (row >= nrows) return;

  const float dv   = *p_dv;
  const float nu   = *p_nu;
  const float dt   = *p_dt;
  const float vmin = ve[0];
  const int   cb   = lane * 16;         // cells cb..cb+7 in .x, cb+8..cb+15 in .y

  // ---- load f: 16 contiguous cells, packed {low 8, high 8} ----
  const float* fp = f + (size_t)row * NVELL + cb;
  v2 fr[8];
  {
    float4 A0 = reinterpret_cast<const float4*>(fp)[0];
    float4 A1 = reinterpret_cast<const float4*>(fp)[1];
    float4 B0 = reinterpret_cast<const float4*>(fp)[2];
    float4 B1 = reinterpret_cast<const float4*>(fp)[3];
    fr[0] = (v2){A0.x, B0.x}; fr[1] = (v2){A0.y, B0.y};
    fr[2] = (v2){A0.z, B0.z}; fr[3] = (v2){A0.w, B0.w};
    fr[4] = (v2){A1.x, B1.x}; fr[5] = (v2){A1.y, B1.y};
    fr[6] = (v2){A1.z, B1.z}; fr[7] = (v2){A1.w, B1.w};
  }

  const float hof = 8.0f * dv;          // offset between .x and .y blocks (exact)
  const float vb0 = __builtin_fmaf((float)cb + 0.5f, dv, vmin);  // exact in f32

  // ---- moments: n, vbar, e_t (accumulate packed, reduce combined via DPP) ----
  v2 sf = bc(0.f), sfv = bc(0.f), sfv2 = bc(0.f);
  {
    v2 vt = (v2){vb0, vb0 + hof};
    #pragma unroll
    for (int i = 0; i < 8; ++i) {
      v2 fv = fr[i] * vt;
      sf   += fr[i];
      sfv  += fv;
      sfv2 += fv * vt;
      vt   += bc(dv);
    }
  }
  const float Sf   = wavesum(sf.x + sf.y);
  const float Sfv  = wavesum(sfv.x + sfv.y);
  const float Sfv2 = wavesum(sfv2.x + sfv2.y);
  const float vbar = Sfv * rcp1(Sf);
  const float nnn  = Sf * dv;
  const float e_t  = dv * __builtin_fmaf(-vbar, Sfv, Sfv2);
  // Self-consistent beta fixed point collapses at f32 (validated R2/R8).
  const float beta = 0.5f * nnn * rcp1(e_t);

  // ---- scalar (wave-uniform) params ----
  const float Dd    = 0.5f * rcp1(beta);
  const float idv   = rcp1(dv);
  const float s     = dt * nu * idv;
  const float twobD = (beta + beta) * Dd;      // mirrors reference 2*beta*D
  const float wfac  = dv * (beta + beta);      // = dv/D up to rcp rounding
  const float kW    = twobD * wfac;            // w = kW*e + cW
  const float cWc   = -(kW * vbar);
  const float Rs    = Dd * (s * idv);          // s*De/dv (interior edges)

  // per-edge alpha/gamma: row i = (a,b,c) = (alpha_L, 1 - gamma_L - alpha_R, gamma_R)
  // alpha = Rs*(w*delta - 1), gamma = Rs*(w*delta - w) - Rs
  // delta via Bernoulli series: 1/2 - w/12 + w^3/720 - w^5/30240
  auto edgeAG = [&](v2 e, v2 &al, v2 &ga) {
    v2 w  = bc(kW) * e + bc(cWc);
    v2 w2 = w * w;
    v2 p  = w2 * bc(-3.30687830e-5f) + bc(1.38888889e-3f);
    p     = w2 * p + bc(-8.33333333e-2f);
    v2 dl = w * p + bc(0.5f);
    v2 t  = w * dl;
    al = bc(Rs) * t - bc(Rs);
    ga = bc(Rs) * (t - w) - bc(Rs);
  };

  // ---- build 8-cell block rows; local Thomas with 3 RHS over interiors 1..6 ----
  const float exl = __builtin_fmaf((float)cb, dv, vmin);   // edge 0 of .x block
  v2 ePos = (v2){exl, exl + hof};

  v2 alA, gaA;
  edgeAG(ePos, alA, gaA);
  if (lane == 0) { alA.x = 0.f; gaA.x = 0.f; }             // global edge 0

  v2 a0v, b0v, c0v, a7v, b7v, c7v;
  v2 cp[7], dpd[7], dps[7], chi6;
  v2 cp_prev = bc(0.f), dpd_prev = bc(0.f), dps_prev = bc(0.f);

  #pragma unroll
  for (int i = 0; i < 8; ++i) {
    ePos += bc(dv);
    v2 alB, gaB;
    edgeAG(ePos, alB, gaB);
    if (i == 7) {
      if (lane == 63) { alB.y = 0.f; gaB.y = 0.f; }        // global edge NV
    }
    // row i: a*x_{i-1} + b*x_i + c*x_{i+1} = f_i
    v2 ai = alA;
    v2 ci = gaB;
    v2 bi = bc(1.f) - gaA - alB;
    if (i == 0)      { a0v = ai; b0v = bi; c0v = ci; }
    else if (i == 7) { a7v = ai; b7v = bi; c7v = ci; }
    else {
      v2 r = rcp2(bi - ai * cp_prev);
      v2 cpi  = (i == 6) ? bc(0.f) : (ci * r);
      if (i == 6) chi6 = -(ci) * r;
      v2 dpdi = (fr[i] - ai * dpd_prev) * r;
      v2 dpsi = (i == 1) ? (-(ai) * r) : ((-(ai) * dps_prev) * r);
      cp[i] = cpi; dpd[i] = dpdi; dps[i] = dpsi;
      cp_prev = cpi; dpd_prev = dpdi; dps_prev = dpsi;
    }
    alA = alB; gaA = gaB;
  }

  // ---- local backward sweep: dpd->phi, dps->psi, cp->chi ----
  cp[6] = chi6;
  #pragma unroll
  for (int i = 5; i >= 1; --i) {
    v2 cpi = cp[i];
    dpd[i] = dpd[i] - cpi * dpd[i+1];
    dps[i] = dps[i] - cpi * dps[i+1];
    cp[i]  = -(cpi) * cp[i+1];
  }
  // x_i = dpd[i] + dps[i]*x_first + cp[i]*x_last  (i=1..6)

  // ---- reduced boundary equations (normalized) ----
  v2 rF = rcp2(b0v + c0v * dps[1]);
  v2 e0a = a0v * rF;                 // couples prev block's LAST
  v2 e0g = (c0v * cp[1]) * rF;       // couples own LAST
  v2 e0d = (fr[0] - c0v * dpd[1]) * rF;

  v2 rL = rcp2(b7v + a7v * cp[6]);
  v2 e1a = (a7v * dps[6]) * rL;      // couples own FIRST
  v2 e1g = c7v * rL;                 // couples next block's FIRST
  v2 e1d = (fr[7] - a7v * dpd[6]) * rL;

  // ---- eliminate LAST -> tridiag in FIRST over 128 adjacent blocks ----
  v2 pa, pg, pd;
  {
    v2 e1aP = blkPrev(e1a, lane);
    v2 e1gP = blkPrev(e1g, lane);
    v2 e1dP = blkPrev(e1d, lane);
    // block 0: e0a == 0 exactly (masked), so zeroed prev values are inert.
    v2 T = rcp2(bc(1.f) - e0a * e1gP - e0g * e1a);
    pa = -(e0a * e1aP) * T;
    pg = -(e0g * e1g) * T;
    pd = (e0d - e0a * e1dP - e0g * e1d) * T;
  }

  // ---- pair elimination: fold odd blocks into even -> 64-unknown scalar tridiag ----
  float sa, sg, sd;
  {
    float paP = __shfl(pa.y, (lane - 1) & 63, 64); if (lane == 0) paP = 0.f;
    float pgP = __shfl(pg.y, (lane - 1) & 63, 64); if (lane == 0) pgP = 0.f;
    float pdP = __shfl(pd.y, (lane - 1) & 63, 64); if (lane == 0) pdP = 0.f;
    // even eq: pa.x*Fodd(L-1) + Fe + pg.x*Fodd(L) = pd.x
    // odd eqs: Fodd(L)  = pd.y  - pa.y*Fe      - pg.y*Fe(L+1)
    //          Fodd(L-1)= pdP   - paP*Fe(L-1)  - pgP*Fe
    float r = rcp1(1.f - pa.x * pgP - pg.x * pa.y);
    sa = -(pa.x * paP) * r;
    sg = -(pg.x * pg.y) * r;
    sd = (pd.x - pa.x * pdP - pg.x * pd.y) * r;
  }

  // ---- scalar PCR over 64 evens: 6 steps ----
  #pragma unroll
  for (int st = 1; st <= 32; st <<= 1) {
    float La = sseamL(sa, lane, st), Lg = sseamL(sg, lane, st), Ld = sseamL(sd, lane, st);
    float Ra = sseamR(sa, lane, st), Rg = sseamR(sg, lane, st), Rd = sseamR(sd, lane, st);
    float r  = rcp1(1.f - sa * Lg - sg * Ra);
    float na = -(sa * La) * r;
    float ng = -(sg * Rg) * r;
    float nd = (sd - sa * Ld - sg * Rd) * r;
    sa = na; sg = ng; sd = nd;
  }
  const float Fe  = sd;                       // F_even(L)
  const float FeN = sseamR(Fe, lane, 1);      // F_even(L+1); lane63: pg.y==0
  const float Fo  = pd.y - pa.y * Fe - pg.y * FeN;

  v2 Fv = (v2){Fe, Fo};                       // FIRST of own blocks
  v2 FvN = blkNext(Fv, lane);                 // FIRST of next block (127: e1g==0)
  v2 Lv = e1d - e1a * Fv - e1g * FvN;         // LAST of own blocks

  v2 x1 = dpd[1] + dps[1] * Fv + cp[1] * Lv;
  v2 x2 = dpd[2] + dps[2] * Fv + cp[2] * Lv;
  v2 x3 = dpd[3] + dps[3] * Fv + cp[3] * Lv;
  v2 x4 = dpd[4] + dps[4] * Fv + cp[4] * Lv;
  v2 x5 = dpd[5] + dps[5] * Fv + cp[5] * Lv;
  v2 x6 = dpd[6] + dps[6] * Fv + cp[6] * Lv;

  float* op = out + (size_t)row * NVELL + cb;
  reinterpret_cast<float4*>(op)[0] = make_float4(Fv.x, x1.x, x2.x, x3.x);
  reinterpret_cast<float4*>(op)[1] = make_float4(x4.x, x5.x, x6.x, Lv.x);
  reinterpret_cast<float4*>(op)[2] = make_float4(Fv.y, x1.y, x2.y, x3.y);
  reinterpret_cast<float4*>(op)[3] = make_float4(x4.y, x5.y, x6.y, Lv.y);
}

extern "C" void kernel_launch(void* const* d_in, const int* in_sizes, int n_in,
                              void* d_out, int out_size, void* d_ws, size_t ws_size,
                              hipStream_t stream) {
  const float* f   = (const float*)d_in[0];
  const float* v   = (const float*)d_in[1];
  const float* ve  = (const float*)d_in[2];
  const float* dvp = (const float*)d_in[3];
  const float* nup = (const float*)d_in[4];
  const float* dtp = (const float*)d_in[5];
  float* out = (float*)d_out;
  int nrows  = in_sizes[0] / NVELL;
  int blocks = (nrows + 3) / 4;
  hipLaunchKernelGGL(fp_step_kernel, dim3(blocks), dim3(256), 0, stream,
                     f, v, ve, dvp, nup, dtp, out, nrows);
}

// Round 12
// 30.520 us; speedup vs baseline: 1.3505x; 1.3505x over previous
//
#include <hip/hip_runtime.h>

#define NVELL 1024

typedef float v2 __attribute__((ext_vector_type(2)));

__device__ __forceinline__ float rcp1(float x){ return __builtin_amdgcn_rcpf(x); }
__device__ __forceinline__ v2 bc(float x){ v2 r = {x, x}; return r; }
__device__ __forceinline__ v2 rcp2(v2 x){ v2 r = {rcp1(x.x), rcp1(x.y)}; return r; }

// 128-position ring: pos = half*64 + lane (half 0 = .x, half 1 = .y).
// seamL/seamR: fetch the triple at pos -/+ st, zero outside [0,128).
__device__ __forceinline__ v2 seamL(v2 p, int lane, int st){
  float sx = __shfl(p.x, (lane - st) & 63, 64);
  float sy = __shfl(p.y, (lane - st) & 63, 64);
  v2 r; r.x = (lane >= st) ? sx : 0.f; r.y = (lane >= st) ? sy : sx; return r;
}
__device__ __forceinline__ v2 seamR(v2 p, int lane, int st){
  float sx = __shfl(p.x, (lane + st) & 63, 64);
  float sy = __shfl(p.y, (lane + st) & 63, 64);
  v2 r; r.x = (lane + st <= 63) ? sx : sy; r.y = (lane + st <= 63) ? sy : 0.f; return r;
}

// ---- DPP wave-sum: row_shr 1,2,4,8 + row_bcast15 + row_bcast31, total in lane 63 ----
template<int CTRL>
__device__ __forceinline__ float dpp_add(float x) {
  float t = __int_as_float(__builtin_amdgcn_update_dpp(
      0, __float_as_int(x), CTRL, 0xf, 0xf, true));
  return x + t;
}
__device__ __forceinline__ float wavesum(float x) {
  x = dpp_add<0x111>(x);   // row_shr:1
  x = dpp_add<0x112>(x);   // row_shr:2
  x = dpp_add<0x114>(x);   // row_shr:4
  x = dpp_add<0x118>(x);   // row_shr:8
  x = dpp_add<0x142>(x);   // row_bcast15
  x = dpp_add<0x143>(x);   // row_bcast31
  return __int_as_float(__builtin_amdgcn_readlane(__float_as_int(x), 63));
}

// Padded LDS layout: cell c -> float index c + 4*(c/32) (16B pad per 128B).
// Dense side: instr k, lane L handles cells 256k+4L.. -> idx 288k + 4L + 4*(L>>3).
// Owned side: cells 8M.. -> idx 8M + 4*(M>>2); cells 512+8M.. -> 576 + 8M + 4*(M>>2).
#define WAVE_LDS_FLOATS 1152

__global__ __launch_bounds__(256, 4) void fp_step_kernel(
    const float* __restrict__ f, const float* __restrict__ v,
    const float* __restrict__ ve, const float* __restrict__ p_dv,
    const float* __restrict__ p_nu, const float* __restrict__ p_dt,
    float* __restrict__ out, int nrows)
{
  __shared__ float lds_all[4 * WAVE_LDS_FLOATS];
  const int lane = threadIdx.x & 63;
  const int wid  = threadIdx.x >> 6;
  const int row  = blockIdx.x * 4 + wid;
  if (row >= nrows) return;
  float* lds = lds_all + wid * WAVE_LDS_FLOATS;

  const float dv   = *p_dv;
  const float nu   = *p_nu;
  const float dt   = *p_dt;
  const float vmin = ve[0];

  // ---- dense global load (unit-stride float4 across lanes) -> LDS stage ----
  const float* frow = f + (size_t)row * NVELL;
  {
    float4 Ld0 = *reinterpret_cast<const float4*>(frow +   0 + 4*lane);
    float4 Ld1 = *reinterpret_cast<const float4*>(frow + 256 + 4*lane);
    float4 Ld2 = *reinterpret_cast<const float4*>(frow + 512 + 4*lane);
    float4 Ld3 = *reinterpret_cast<const float4*>(frow + 768 + 4*lane);
    const int wb = 4*lane + 4*(lane >> 3);
    *reinterpret_cast<float4*>(lds +   0 + wb) = Ld0;
    *reinterpret_cast<float4*>(lds + 288 + wb) = Ld1;
    *reinterpret_cast<float4*>(lds + 576 + wb) = Ld2;
    *reinterpret_cast<float4*>(lds + 864 + wb) = Ld3;
  }

  // ---- read owned split-half layout: .x = cells 8L..8L+7, .y = 512+8L.. ----
  v2 fr[8];
  {
    const int rb = 8*lane + 4*(lane >> 2);
    float4 A0 = *reinterpret_cast<float4*>(lds + rb);
    float4 A1 = *reinterpret_cast<float4*>(lds + rb + 4);
    float4 B0 = *reinterpret_cast<float4*>(lds + 576 + rb);
    float4 B1 = *reinterpret_cast<float4*>(lds + 576 + rb + 4);
    fr[0] = (v2){A0.x, B0.x}; fr[1] = (v2){A0.y, B0.y};
    fr[2] = (v2){A0.z, B0.z}; fr[3] = (v2){A0.w, B0.w};
    fr[4] = (v2){A1.x, B1.x}; fr[5] = (v2){A1.y, B1.y};
    fr[6] = (v2){A1.z, B1.z}; fr[7] = (v2){A1.w, B1.w};
  }

  const int   cb  = lane * 8;
  const float half_off = 512.0f * dv;   // = 6.0 exactly
  const float vb0 = __builtin_fmaf((float)cb + 0.5f, dv, vmin);  // exact in f32

  // ---- moments: n, vbar, e_t (accumulate packed, reduce combined via DPP) ----
  v2 sf = bc(0.f), sfv = bc(0.f), sfv2 = bc(0.f);
  {
    v2 vt = (v2){vb0, vb0 + half_off};
    #pragma unroll
    for (int i = 0; i < 8; ++i) {
      v2 fv = fr[i] * vt;
      sf   += fr[i];
      sfv  += fv;
      sfv2 += fv * vt;
      vt   += bc(dv);
    }
  }
  const float Sf   = wavesum(sf.x + sf.y);
  const float Sfv  = wavesum(sfv.x + sfv.y);
  const float Sfv2 = wavesum(sfv2.x + sfv2.y);
  const float vbar = Sfv * rcp1(Sf);
  const float nnn  = Sf * dv;
  const float e_t  = dv * __builtin_fmaf(-vbar, Sfv, Sfv2);
  // Self-consistent beta fixed point collapses at f32 (validated R2/R8).
  const float beta = 0.5f * nnn * rcp1(e_t);

  // ---- scalar (wave-uniform) params ----
  const float Dd    = 0.5f * rcp1(beta);
  const float idv   = rcp1(dv);
  const float s     = dt * nu * idv;
  const float twobD = (beta + beta) * Dd;      // mirrors reference 2*beta*D
  const float wfac  = dv * (beta + beta);      // = dv/D up to rcp rounding
  const float kW    = twobD * wfac;            // w = kW*e + cW
  const float cWc   = -(kW * vbar);
  const float Rs    = Dd * (s * idv);          // s*De/dv (interior edges)

  // per-edge alpha/gamma: row i = (a,b,c) = (alpha_L, 1 - gamma_L - alpha_R, gamma_R)
  // alpha = Rs*(w*delta - 1), gamma = Rs*(w*delta - w) - Rs
  // delta via Bernoulli series: 1/2 - w/12 + w^3/720 - w^5/30240
  auto edgeAG = [&](v2 e, v2 &al, v2 &ga) {
    v2 w  = bc(kW) * e + bc(cWc);
    v2 w2 = w * w;
    v2 p  = w2 * bc(-3.30687830e-5f) + bc(1.38888889e-3f);
    p     = w2 * p + bc(-8.33333333e-2f);
    v2 dl = w * p + bc(0.5f);
    v2 t  = w * dl;
    al = bc(Rs) * t - bc(Rs);
    ga = bc(Rs) * (t - w) - bc(Rs);
  };

  // ---- build 8-cell block rows; local Thomas with 3 RHS over interiors 1..6 ----
  const float exl = __builtin_fmaf((float)cb, dv, vmin);   // edge 0 of .x block
  v2 ePos = (v2){exl, exl + half_off};

  v2 alA, gaA;
  edgeAG(ePos, alA, gaA);
  if (lane == 0) { alA.x = 0.f; gaA.x = 0.f; }             // global edge 0

  v2 a0v, b0v, c0v, a7v, b7v, c7v;
  v2 cp[7], dpd[7], dps[7], chi6;
  v2 cp_prev = bc(0.f), dpd_prev = bc(0.f), dps_prev = bc(0.f);

  #pragma unroll
  for (int i = 0; i < 8; ++i) {
    ePos += bc(dv);
    v2 alB, gaB;
    edgeAG(ePos, alB, gaB);
    if (i == 7) {
      if (lane == 63) { alB.y = 0.f; gaB.y = 0.f; }        // global edge NV
    }
    // row i: a*x_{i-1} + b*x_i + c*x_{i+1} = f_i
    v2 ai = alA;
    v2 ci = gaB;
    v2 bi = bc(1.f) - gaA - alB;
    if (i == 0)      { a0v = ai; b0v = bi; c0v = ci; }
    else if (i == 7) { a7v = ai; b7v = bi; c7v = ci; }
    else {
      v2 r = rcp2(bi - ai * cp_prev);
      v2 cpi  = (i == 6) ? bc(0.f) : (ci * r);
      if (i == 6) chi6 = -(ci) * r;
      v2 dpdi = (fr[i] - ai * dpd_prev) * r;
      v2 dpsi = (i == 1) ? (-(ai) * r) : ((-(ai) * dps_prev) * r);
      cp[i] = cpi; dpd[i] = dpdi; dps[i] = dpsi;
      cp_prev = cpi; dpd_prev = dpdi; dps_prev = dpsi;
    }
    alA = alB; gaA = gaB;
  }

  // ---- local backward sweep: dpd->phi, dps->psi, cp->chi ----
  cp[6] = chi6;
  #pragma unroll
  for (int i = 5; i >= 1; --i) {
    v2 cpi = cp[i];
    dpd[i] = dpd[i] - cpi * dpd[i+1];
    dps[i] = dps[i] - cpi * dps[i+1];
    cp[i]  = -(cpi) * cp[i+1];
  }
  // x_i = dpd[i] + dps[i]*x_first + cp[i]*x_last  (i=1..6)

  // ---- reduced boundary equations (normalized) ----
  v2 rF = rcp2(b0v + c0v * dps[1]);
  v2 e0a = a0v * rF;                 // couples prev block's LAST
  v2 e0g = (c0v * cp[1]) * rF;       // couples own LAST
  v2 e0d = (fr[0] - c0v * dpd[1]) * rF;

  v2 rL = rcp2(b7v + a7v * cp[6]);
  v2 e1a = (a7v * dps[6]) * rL;      // couples own FIRST
  v2 e1g = c7v * rL;                 // couples next block's FIRST
  v2 e1d = (fr[7] - a7v * dpd[6]) * rL;

  // ---- eliminate LAST -> 128-ring tridiagonal in FIRST ----
  v2 pa, pg, pd;
  {
    v2 e1aP = seamL(e1a, lane, 1);
    v2 e1gP = seamL(e1g, lane, 1);
    v2 e1dP = seamL(e1d, lane, 1);
    // pos 0: e0a == 0 exactly (masked), so the zeroed prev values are inert.
    v2 T = rcp2(bc(1.f) - e0a * e1gP - e0g * e1a);
    pa = -(e0a * e1aP) * T;
    pg = -(e0g * e1g) * T;
    pd = (e0d - e0a * e1dP - e0g * e1d) * T;
  }

  // ---- PCR over the 128-ring: 6 shuffle steps + 1 component-swap step ----
  #pragma unroll
  for (int st = 1; st <= 32; st <<= 1) {
    v2 La = seamL(pa, lane, st), Lg = seamL(pg, lane, st), Ld = seamL(pd, lane, st);
    v2 Ra = seamR(pa, lane, st), Rg = seamR(pg, lane, st), Rd = seamR(pd, lane, st);
    v2 r   = rcp2(bc(1.f) - pa * Lg - pg * Ra);
    v2 npa = -(pa * La) * r;
    v2 npg = -(pg * Rg) * r;
    v2 npd = (pd - pa * Ld - pg * Rd) * r;
    pa = npa; pg = npg; pd = npd;
  }
  {
    // st = 64: left/right neighbors are the other component of the same lane.
    v2 La = (v2){0.f, pa.x}, Lg = (v2){0.f, pg.x}, Ld = (v2){0.f, pd.x};
    v2 Ra = (v2){pa.y, 0.f}, Rg = (v2){pg.y, 0.f}, Rd = (v2){pd.y, 0.f};
    v2 r   = rcp2(bc(1.f) - pa * Lg - pg * Ra);
    v2 npd = (pd - pa * Ld - pg * Rd) * r;
    pd = npd;
  }

  // ---- recover LAST and interiors ----
  v2 Fv = pd;                        // x_first of own blocks
  v2 Fn = seamR(Fv, lane, 1);        // x_first of next block (pos 127: e1g==0)
  v2 Lv = e1d - e1a * Fv - e1g * Fn; // x_last of own blocks

  v2 x1 = dpd[1] + dps[1] * Fv + cp[1] * Lv;
  v2 x2 = dpd[2] + dps[2] * Fv + cp[2] * Lv;
  v2 x3 = dpd[3] + dps[3] * Fv + cp[3] * Lv;
  v2 x4 = dpd[4] + dps[4] * Fv + cp[4] * Lv;
  v2 x5 = dpd[5] + dps[5] * Fv + cp[5] * Lv;
  v2 x6 = dpd[6] + dps[6] * Fv + cp[6] * Lv;

  // ---- owned results -> LDS (same padded addresses) -> dense global store ----
  {
    const int rb = 8*lane + 4*(lane >> 2);
    *reinterpret_cast<float4*>(lds + rb)           = make_float4(Fv.x, x1.x, x2.x, x3.x);
    *reinterpret_cast<float4*>(lds + rb + 4)       = make_float4(x4.x, x5.x, x6.x, Lv.x);
    *reinterpret_cast<float4*>(lds + 576 + rb)     = make_float4(Fv.y, x1.y, x2.y, x3.y);
    *reinterpret_cast<float4*>(lds + 576 + rb + 4) = make_float4(x4.y, x5.y, x6.y, Lv.y);
  }
  {
    const int wb = 4*lane + 4*(lane >> 3);
    float4 S0 = *reinterpret_cast<float4*>(lds +   0 + wb);
    float4 S1 = *reinterpret_cast<float4*>(lds + 288 + wb);
    float4 S2 = *reinterpret_cast<float4*>(lds + 576 + wb);
    float4 S3 = *reinterpret_cast<float4*>(lds + 864 + wb);
    float* orow = out + (size_t)row * NVELL;
    *reinterpret_cast<float4*>(orow +   0 + 4*lane) = S0;
    *reinterpret_cast<float4*>(orow + 256 + 4*lane) = S1;
    *reinterpret_cast<float4*>(orow + 512 + 4*lane) = S2;
    *reinterpret_cast<float4*>(orow + 768 + 4*lane) = S3;
  }
}

extern "C" void kernel_launch(void* const* d_in, const int* in_sizes, int n_in,
                              void* d_out, int out_size, void* d_ws, size_t ws_size,
                              hipStream_t stream) {
  const float* f   = (const float*)d_in[0];
  const float* v   = (const float*)d_in[1];
  const float* ve  = (const float*)d_in[2];
  const float* dvp = (const float*)d_in[3];
  const float* nup = (const float*)d_in[4];
  const float* dtp = (const float*)d_in[5];
  float* out = (float*)d_out;
  int nrows  = in_sizes[0] / NVELL;
  int blocks = (nrows + 3) / 4;
  hipLaunchKernelGGL(fp_step_kernel, dim3(blocks), dim3(256), 0, stream,
                     f, v, ve, dvp, nup, dtp, out, nrows);
}

// Round 13
// 30.435 us; speedup vs baseline: 1.3543x; 1.0028x over previous
//
#include <hip/hip_runtime.h>

#define NVELL 1024

typedef float v2 __attribute__((ext_vector_type(2)));

__device__ __forceinline__ float rcp1(float x){ return __builtin_amdgcn_rcpf(x); }
__device__ __forceinline__ v2 bc(float x){ v2 r = {x, x}; return r; }
__device__ __forceinline__ v2 rcp2(v2 x){ v2 r = {rcp1(x.x), rcp1(x.y)}; return r; }

// 128-position ring: pos = half*64 + lane (half 0 = .x, half 1 = .y).
// seamL/seamR: fetch the triple at pos -/+ st, zero outside [0,128).
__device__ __forceinline__ v2 seamL(v2 p, int lane, int st){
  float sx = __shfl(p.x, (lane - st) & 63, 64);
  float sy = __shfl(p.y, (lane - st) & 63, 64);
  v2 r; r.x = (lane >= st) ? sx : 0.f; r.y = (lane >= st) ? sy : sx; return r;
}
__device__ __forceinline__ v2 seamR(v2 p, int lane, int st){
  float sx = __shfl(p.x, (lane + st) & 63, 64);
  float sy = __shfl(p.y, (lane + st) & 63, 64);
  v2 r; r.x = (lane + st <= 63) ? sx : sy; r.y = (lane + st <= 63) ? sy : 0.f; return r;
}

// ---- DPP wave-sum: row_shr 1,2,4,8 + row_bcast15 + row_bcast31, total in lane 63 ----
template<int CTRL>
__device__ __forceinline__ float dpp_add(float x) {
  float t = __int_as_float(__builtin_amdgcn_update_dpp(
      0, __float_as_int(x), CTRL, 0xf, 0xf, true));
  return x + t;
}
__device__ __forceinline__ float wavesum(float x) {
  x = dpp_add<0x111>(x);   // row_shr:1
  x = dpp_add<0x112>(x);   // row_shr:2
  x = dpp_add<0x114>(x);   // row_shr:4
  x = dpp_add<0x118>(x);   // row_shr:8
  x = dpp_add<0x142>(x);   // row_bcast15
  x = dpp_add<0x143>(x);   // row_bcast31
  return __int_as_float(__builtin_amdgcn_readlane(__float_as_int(x), 63));
}

// Full solve for one row, given its 4 preloaded float4s (R8-validated body).
__device__ __forceinline__ void solve_row(
    float4 A0, float4 A1, float4 B0, float4 B1,
    float* __restrict__ orow, int lane,
    float dv, float nu, float dt, float vmin)
{
  v2 fr[8];
  fr[0] = (v2){A0.x, B0.x}; fr[1] = (v2){A0.y, B0.y};
  fr[2] = (v2){A0.z, B0.z}; fr[3] = (v2){A0.w, B0.w};
  fr[4] = (v2){A1.x, B1.x}; fr[5] = (v2){A1.y, B1.y};
  fr[6] = (v2){A1.z, B1.z}; fr[7] = (v2){A1.w, B1.w};

  const int   cb       = lane * 8;
  const float half_off = 512.0f * dv;   // = 6.0 exactly
  const float vb0 = __builtin_fmaf((float)cb + 0.5f, dv, vmin);  // exact in f32

  // ---- moments: n, vbar, e_t (accumulate packed, reduce combined via DPP) ----
  v2 sf = bc(0.f), sfv = bc(0.f), sfv2 = bc(0.f);
  {
    v2 vt = (v2){vb0, vb0 + half_off};
    #pragma unroll
    for (int i = 0; i < 8; ++i) {
      v2 fv = fr[i] * vt;
      sf   += fr[i];
      sfv  += fv;
      sfv2 += fv * vt;
      vt   += bc(dv);
    }
  }
  const float Sf   = wavesum(sf.x + sf.y);
  const float Sfv  = wavesum(sfv.x + sfv.y);
  const float Sfv2 = wavesum(sfv2.x + sfv2.y);
  const float vbar = Sfv * rcp1(Sf);
  const float nnn  = Sf * dv;
  const float e_t  = dv * __builtin_fmaf(-vbar, Sfv, Sfv2);
  // Self-consistent beta fixed point collapses at f32 (validated R2/R8).
  const float beta = 0.5f * nnn * rcp1(e_t);

  // ---- scalar (wave-uniform) params ----
  const float Dd    = 0.5f * rcp1(beta);
  const float idv   = rcp1(dv);
  const float s     = dt * nu * idv;
  const float twobD = (beta + beta) * Dd;      // mirrors reference 2*beta*D
  const float wfac  = dv * (beta + beta);      // = dv/D up to rcp rounding
  const float kW    = twobD * wfac;            // w = kW*e + cW
  const float cWc   = -(kW * vbar);
  const float Rs    = Dd * (s * idv);          // s*De/dv (interior edges)

  // per-edge alpha/gamma: row i = (a,b,c) = (alpha_L, 1 - gamma_L - alpha_R, gamma_R)
  auto edgeAG = [&](v2 e, v2 &al, v2 &ga) {
    v2 w  = bc(kW) * e + bc(cWc);
    v2 w2 = w * w;
    v2 p  = w2 * bc(-3.30687830e-5f) + bc(1.38888889e-3f);
    p     = w2 * p + bc(-8.33333333e-2f);
    v2 dl = w * p + bc(0.5f);
    v2 t  = w * dl;
    al = bc(Rs) * t - bc(Rs);
    ga = bc(Rs) * (t - w) - bc(Rs);
  };

  // ---- build 8-cell block rows; local Thomas with 3 RHS over interiors 1..6 ----
  const float exl = __builtin_fmaf((float)cb, dv, vmin);   // edge 0 of .x block
  v2 ePos = (v2){exl, exl + half_off};

  v2 alA, gaA;
  edgeAG(ePos, alA, gaA);
  if (lane == 0) { alA.x = 0.f; gaA.x = 0.f; }             // global edge 0

  v2 a0v, b0v, c0v, a7v, b7v, c7v;
  v2 cp[7], dpd[7], dps[7], chi6;
  v2 cp_prev = bc(0.f), dpd_prev = bc(0.f), dps_prev = bc(0.f);

  #pragma unroll
  for (int i = 0; i < 8; ++i) {
    ePos += bc(dv);
    v2 alB, gaB;
    edgeAG(ePos, alB, gaB);
    if (i == 7) {
      if (lane == 63) { alB.y = 0.f; gaB.y = 0.f; }        // global edge NV
    }
    v2 ai = alA;
    v2 ci = gaB;
    v2 bi = bc(1.f) - gaA - alB;
    if (i == 0)      { a0v = ai; b0v = bi; c0v = ci; }
    else if (i == 7) { a7v = ai; b7v = bi; c7v = ci; }
    else {
      v2 r = rcp2(bi - ai * cp_prev);
      v2 cpi  = (i == 6) ? bc(0.f) : (ci * r);
      if (i == 6) chi6 = -(ci) * r;
      v2 dpdi = (fr[i] - ai * dpd_prev) * r;
      v2 dpsi = (i == 1) ? (-(ai) * r) : ((-(ai) * dps_prev) * r);
      cp[i] = cpi; dpd[i] = dpdi; dps[i] = dpsi;
      cp_prev = cpi; dpd_prev = dpdi; dps_prev = dpsi;
    }
    alA = alB; gaA = gaB;
  }

  // ---- local backward sweep: dpd->phi, dps->psi, cp->chi ----
  cp[6] = chi6;
  #pragma unroll
  for (int i = 5; i >= 1; --i) {
    v2 cpi = cp[i];
    dpd[i] = dpd[i] - cpi * dpd[i+1];
    dps[i] = dps[i] - cpi * dps[i+1];
    cp[i]  = -(cpi) * cp[i+1];
  }

  // ---- reduced boundary equations (normalized) ----
  v2 rF = rcp2(b0v + c0v * dps[1]);
  v2 e0a = a0v * rF;
  v2 e0g = (c0v * cp[1]) * rF;
  v2 e0d = (fr[0] - c0v * dpd[1]) * rF;

  v2 rL = rcp2(b7v + a7v * cp[6]);
  v2 e1a = (a7v * dps[6]) * rL;
  v2 e1g = c7v * rL;
  v2 e1d = (fr[7] - a7v * dpd[6]) * rL;

  // ---- eliminate LAST -> 128-ring tridiagonal in FIRST ----
  v2 pa, pg, pd;
  {
    v2 e1aP = seamL(e1a, lane, 1);
    v2 e1gP = seamL(e1g, lane, 1);
    v2 e1dP = seamL(e1d, lane, 1);
    v2 T = rcp2(bc(1.f) - e0a * e1gP - e0g * e1a);
    pa = -(e0a * e1aP) * T;
    pg = -(e0g * e1g) * T;
    pd = (e0d - e0a * e1dP - e0g * e1d) * T;
  }

  // ---- PCR over the 128-ring: 6 shuffle steps + 1 component-swap step ----
  #pragma unroll
  for (int st = 1; st <= 32; st <<= 1) {
    v2 La = seamL(pa, lane, st), Lg = seamL(pg, lane, st), Ld = seamL(pd, lane, st);
    v2 Ra = seamR(pa, lane, st), Rg = seamR(pg, lane, st), Rd = seamR(pd, lane, st);
    v2 r   = rcp2(bc(1.f) - pa * Lg - pg * Ra);
    v2 npa = -(pa * La) * r;
    v2 npg = -(pg * Rg) * r;
    v2 npd = (pd - pa * Ld - pg * Rd) * r;
    pa = npa; pg = npg; pd = npd;
  }
  {
    v2 La = (v2){0.f, pa.x}, Lg = (v2){0.f, pg.x}, Ld = (v2){0.f, pd.x};
    v2 Ra = (v2){pa.y, 0.f}, Rg = (v2){pg.y, 0.f}, Rd = (v2){pd.y, 0.f};
    v2 r   = rcp2(bc(1.f) - pa * Lg - pg * Ra);
    v2 npd = (pd - pa * Ld - pg * Rd) * r;
    pd = npd;
  }

  // ---- recover LAST and interiors ----
  v2 Fv = pd;
  v2 Fn = seamR(Fv, lane, 1);
  v2 Lv = e1d - e1a * Fv - e1g * Fn;

  v2 x1 = dpd[1] + dps[1] * Fv + cp[1] * Lv;
  v2 x2 = dpd[2] + dps[2] * Fv + cp[2] * Lv;
  v2 x3 = dpd[3] + dps[3] * Fv + cp[3] * Lv;
  v2 x4 = dpd[4] + dps[4] * Fv + cp[4] * Lv;
  v2 x5 = dpd[5] + dps[5] * Fv + cp[5] * Lv;
  v2 x6 = dpd[6] + dps[6] * Fv + cp[6] * Lv;

  float* op = orow + cb;
  reinterpret_cast<float4*>(op)[0]       = make_float4(Fv.x, x1.x, x2.x, x3.x);
  reinterpret_cast<float4*>(op)[1]       = make_float4(x4.x, x5.x, x6.x, Lv.x);
  reinterpret_cast<float4*>(op + 512)[0] = make_float4(Fv.y, x1.y, x2.y, x3.y);
  reinterpret_cast<float4*>(op + 512)[1] = make_float4(x4.y, x5.y, x6.y, Lv.y);
}

__global__ __launch_bounds__(256, 4) void fp_step_kernel(
    const float* __restrict__ f, const float* __restrict__ v,
    const float* __restrict__ ve, const float* __restrict__ p_dv,
    const float* __restrict__ p_nu, const float* __restrict__ p_dt,
    float* __restrict__ out, int nrows)
{
  const int lane = threadIdx.x & 63;
  const int wid  = threadIdx.x >> 6;
  const int rowA = blockIdx.x * 8 + wid * 2;
  if (rowA >= nrows) return;
  const int rowB = (rowA + 1 < nrows) ? (rowA + 1) : rowA;

  const float dv   = *p_dv;
  const float nu   = *p_nu;
  const float dt   = *p_dt;
  const float vmin = ve[0];
  const int   cb   = lane * 8;

  // ---- issue ALL loads for BOTH rows up front (8 dwordx4 in flight).
  // Row A's first use forces vmcnt(4): B's loads stay outstanding and their
  // ~600-900 cy HBM latency is hidden under row A's ~2000 cy solve.
  const float* fpA = f + (size_t)rowA * NVELL + cb;
  const float* fpB = f + (size_t)rowB * NVELL + cb;
  float4 A0 = reinterpret_cast<const float4*>(fpA)[0];
  float4 A1 = reinterpret_cast<const float4*>(fpA)[1];
  float4 A2 = reinterpret_cast<const float4*>(fpA + 512)[0];
  float4 A3 = reinterpret_cast<const float4*>(fpA + 512)[1];
  float4 Bb0 = reinterpret_cast<const float4*>(fpB)[0];
  float4 Bb1 = reinterpret_cast<const float4*>(fpB)[1];
  float4 Bb2 = reinterpret_cast<const float4*>(fpB + 512)[0];
  float4 Bb3 = reinterpret_cast<const float4*>(fpB + 512)[1];

  solve_row(A0, A1, A2, A3, out + (size_t)rowA * NVELL, lane, dv, nu, dt, vmin);
  solve_row(Bb0, Bb1, Bb2, Bb3, out + (size_t)rowB * NVELL, lane, dv, nu, dt, vmin);
}

extern "C" void kernel_launch(void* const* d_in, const int* in_sizes, int n_in,
                              void* d_out, int out_size, void* d_ws, size_t ws_size,
                              hipStream_t stream) {
  const float* f   = (const float*)d_in[0];
  const float* v   = (const float*)d_in[1];
  const float* ve  = (const float*)d_in[2];
  const float* dvp = (const float*)d_in[3];
  const float* nup = (const float*)d_in[4];
  const float* dtp = (const float*)d_in[5];
  float* out = (float*)d_out;
  int nrows  = in_sizes[0] / NVELL;
  int blocks = (nrows + 7) / 8;
  hipLaunchKernelGGL(fp_step_kernel, dim3(blocks), dim3(256), 0, stream,
                     f, v, ve, dvp, nup, dtp, out, nrows);
}